// Round 10
// baseline (2967.408 us; speedup 1.0000x reference)
//
#include <hip/hip_runtime.h>
#include <math.h>

// Problem constants: B=512, T=2048, D=10, H=20
#define BB 512
#define TT 2048
#define DD 10
#define HH 20
#define BH (BB*HH)          // 10240 elements per timestep
#define NW 4                // k_rnn worker blocks (1 CU each, same XCD)
#define BPB (BB / NW)       // batches per worker block (128)

// ws layout (word indices from base)
#define WS_AMAX     0
#define WS_PROD_XWI 4
#define WS_INV_SX   5
#define WS_S_H0     6
#define WS_INV_SH0  7
#define WS_S_WH     8
#define WS_BQ       16
#define WS_WIP      40
#define WS_WHP      104
// cross-block sync (cleared by the 4096B memset each launch).
// One 128B region per block (no false/line sharing):
//  flag words:   SYNF + blk*32 + (t&1)*16 -> ((t+1)<<8) | flags
//  rare extrema: SYNR + blk*32 + (t&1)*16 + {0:mx,1:mn,2:tag}
#define SYNF 512
#define SYNR 768
#define WS_XW_OFF   4096    // byte offset of xW buffer: [T][B][H] floats (84 MB)
// per-row reuse: after step t consumes xw row t, k_rnn writes packed int8 levels
// into dwords [0..2559] ({hd0,hd1}@2b, {hd2,hd3}@1024+2b, hd4@2048+b) and
// sh[t] bits into dword 2560 of that row. k_tr reconstructs level*sh exactly.

// LDS-only barrier: never drains vmcnt (prefetch loads / output stores stay in flight)
#define BAR() asm volatile("s_waitcnt lgkmcnt(0)\n\ts_barrier" ::: "memory")

__device__ __forceinline__ int dot4(int a, int b, int c) {
    return __builtin_amdgcn_sdot4(a, b, c, false);
}

// scale = exp2(ceil(log2(max(m,1e-10))))/128 via exponent bits (exact, branchless)
__device__ __forceinline__ void p2s(float m, float* s, float* is) {
    m = fmaxf(m, 1e-10f);
    unsigned u = __float_as_uint(m);
    int k = (int)(u >> 23) - 127 + ((u & 0x7fffffu) ? 1 : 0);  // ceil(log2(m))
    *s  = __uint_as_float((unsigned)(k + 120) << 23);           // 2^(k-7)
    *is = __uint_as_float((unsigned)(134 - k) << 23);           // 2^(7-k)
}

__device__ __forceinline__ float fmed3(float a, float b, float c) {
    return __builtin_amdgcn_fmed3f(a, b, c);
}

__device__ __forceinline__ int qlevel(float v, float inv) {
    return (int)fmed3(rintf(v * inv), -128.f, 127.f);
}

__device__ __forceinline__ int pack4(int a, int b, int c, int d) {
    return (a & 255) | ((b & 255) << 8) | ((c & 255) << 16) | ((d & 255) << 24);
}

// DPP with compile-time ctrl (builtin requires ICE args -> template params).
// old = m, bound_ctrl = 0: lanes with no valid source keep their own value --
// a no-op under max/min, so safe for ANY sign.
template<int CTRL, int RM>
__device__ __forceinline__ float fdpp(float m) {
    return __int_as_float(__builtin_amdgcn_update_dpp(
        __float_as_int(m), __float_as_int(m), CTRL, RM, 0xf, false));
}
// wave64 max: lane63 holds the full-wave max
__device__ __forceinline__ float wave_fmax(float m) {
    m = fmaxf(m, fdpp<0x111, 0xf>(m));  // row_shr1
    m = fmaxf(m, fdpp<0x112, 0xf>(m));  // row_shr2
    m = fmaxf(m, fdpp<0x114, 0xf>(m));  // row_shr4
    m = fmaxf(m, fdpp<0x118, 0xf>(m));  // row_shr8
    m = fmaxf(m, fdpp<0x142, 0xa>(m));  // row_bcast15
    m = fmaxf(m, fdpp<0x143, 0xc>(m));  // row_bcast31
    return m;
}
__device__ __forceinline__ float wave_fmin(float m) {
    m = fminf(m, fdpp<0x111, 0xf>(m));
    m = fminf(m, fdpp<0x112, 0xf>(m));
    m = fminf(m, fdpp<0x114, 0xf>(m));
    m = fminf(m, fdpp<0x118, 0xf>(m));
    m = fminf(m, fdpp<0x142, 0xa>(m));
    m = fminf(m, fdpp<0x143, 0xc>(m));
    return m;
}
// cyclic 16-lane-row reduce: every lane gets its row's max/min
__device__ __forceinline__ float row_fmax(float m) {
    m = fmaxf(m, fdpp<0x121, 0xf>(m));  // row_ror1
    m = fmaxf(m, fdpp<0x122, 0xf>(m));  // row_ror2
    m = fmaxf(m, fdpp<0x124, 0xf>(m));  // row_ror4
    m = fmaxf(m, fdpp<0x128, 0xf>(m));  // row_ror8
    return m;
}
__device__ __forceinline__ float row_fmin(float m) {
    m = fminf(m, fdpp<0x121, 0xf>(m));
    m = fminf(m, fdpp<0x122, 0xf>(m));
    m = fminf(m, fdpp<0x124, 0xf>(m));
    m = fminf(m, fdpp<0x128, 0xf>(m));
    return m;
}

// ceil(log2(max(tanh(mf*sa),1e-10))) -- exponent of the h scale for level mf
__device__ __forceinline__ int khof(float mf, float sa) {
    float mh = fmaxf(tanhf(mf * sa), 1e-10f);
    unsigned u = __float_as_uint(mh);
    return (int)(u >> 23) - 127 + ((u & 0x7fffffu) ? 1 : 0);
}

// pair (lanes 2k,2k+1) h-level merge: 3 quad_perm DPP + byte splices -> hd[5]
// callers guarantee PC fits in 16 bits and PA/PB bytes are pre-masked.
__device__ __forceinline__ void mk_hd(int PA, int PB, int PC, bool isLo, int* hd) {
    int QA = __builtin_amdgcn_update_dpp(0, PA, 0xB1, 0xf, 0xf, true); // quad_perm [1,0,3,2]
    int QB = __builtin_amdgcn_update_dpp(0, PB, 0xB1, 0xf, 0xf, true);
    int QC = __builtin_amdgcn_update_dpp(0, PC, 0xB1, 0xf, 0xf, true);
    int XA = isLo ? PA : QA, XB = isLo ? PB : QB, XC = isLo ? PC : QC;
    int YA = isLo ? QA : PA, YB = isLo ? QB : PB, YC = isLo ? QC : PC;
    hd[0] = XA; hd[1] = XB;
    hd[2] = XC | (YA << 16);
    hd[3] = (int)((unsigned)YA >> 16) | (YB << 16);
    hd[4] = (int)((unsigned)YB >> 16) | (YC << 16);
}

// ---------------- kernel 1: maxabs(x) grid reduction -------------------------
__global__ void k_amax(const float* __restrict__ x, int n4, unsigned* amax) {
    int g = blockIdx.x * blockDim.x + threadIdx.x;
    int stride = gridDim.x * blockDim.x;
    const float4* xv = (const float4*)x;
    float m = 0.f;
    for (int i = g; i < n4; i += stride) {
        float4 v = xv[i];
        m = fmaxf(m, fmaxf(fmaxf(fabsf(v.x), fabsf(v.y)), fmaxf(fabsf(v.z), fabsf(v.w))));
    }
#pragma unroll
    for (int off = 32; off; off >>= 1) m = fmaxf(m, __shfl_xor(m, off, 64));
    if ((threadIdx.x & 63) == 0) atomicMax(amax, __float_as_uint(m));
}

// ---------------- kernel 2: scales + weight quant/pack -----------------------
__device__ float bmaxabs(const float* p, int n, float* red, int tid) {
    float m = 0.f;
    for (int i = tid; i < n; i += 256) m = fmaxf(m, fabsf(p[i]));
    red[tid] = m; __syncthreads();
    for (int s = 128; s; s >>= 1) {
        if (tid < s) red[tid] = fmaxf(red[tid], red[tid + s]);
        __syncthreads();
    }
    m = red[0]; __syncthreads();
    return m;
}

__global__ void k_prep(const float* __restrict__ Wi, const float* __restrict__ Wh,
                       const float* __restrict__ bias, const float* __restrict__ h0,
                       float* wsf, int* wsi) {
    __shared__ float red[256];
    __shared__ float hdr[4];
    int tid = threadIdx.x;
    float mwi = bmaxabs(Wi, HH * DD, red, tid);
    float mwh = bmaxabs(Wh, HH * HH, red, tid);
    float mb  = bmaxabs(bias, HH, red, tid);
    float mh0 = bmaxabs(h0, BH, red, tid);
    if (tid == 0) {
        float mx = __uint_as_float(((unsigned*)wsf)[WS_AMAX]);
        float sx, isx, swi, iswi, swh, iswh, sb, isb, sh0, ish0;
        p2s(mx,  &sx,  &isx);
        p2s(mwi, &swi, &iswi);
        p2s(mwh, &swh, &iswh);
        p2s(mb,  &sb,  &isb);
        p2s(mh0, &sh0, &ish0);
        wsf[WS_PROD_XWI] = sx * swi;
        wsf[WS_INV_SX]   = isx;
        wsf[WS_S_H0]     = sh0;
        wsf[WS_INV_SH0]  = ish0;
        wsf[WS_S_WH]     = swh;
        hdr[0] = iswi; hdr[1] = iswh; hdr[2] = sb; hdr[3] = isb;
    }
    __syncthreads();
    if (tid < HH) {
        float iswi = hdr[0], iswh = hdr[1], sb = hdr[2], isb = hdr[3];
        int lv[20];
#pragma unroll
        for (int d = 0; d < DD; ++d) lv[d] = qlevel(Wi[tid * DD + d], iswi);
        lv[10] = 0; lv[11] = 0;
#pragma unroll
        for (int k = 0; k < 3; ++k)
            wsi[WS_WIP + tid * 3 + k] = pack4(lv[4*k], lv[4*k+1], lv[4*k+2], lv[4*k+3]);
#pragma unroll
        for (int k = 0; k < HH; ++k) lv[k] = qlevel(Wh[tid * HH + k], iswh);
#pragma unroll
        for (int k = 0; k < 5; ++k)
            wsi[WS_WHP + tid * 5 + k] = pack4(lv[4*k], lv[4*k+1], lv[4*k+2], lv[4*k+3]);
        wsf[WS_BQ + tid] = (float)qlevel(bias[tid], isb) * sb;
    }
}

// ---------------- kernel 3: xW[t][b][j] = quant(x)·Wi_q + bq -----------------
__global__ __launch_bounds__(256) void k_xw(const float* __restrict__ x,
                                            const float* __restrict__ wsf,
                                            const int* __restrict__ wsi,
                                            float* __restrict__ xw) {
    int g = blockIdx.x * 256 + threadIdx.x;
    int b = g & (BB - 1);
    int t = g >> 9;
    float isx  = wsf[WS_INV_SX];
    float prod = wsf[WS_PROD_XWI];
    const float2* xp = (const float2*)(x + ((size_t)b * TT + t) * DD);
    float xv[10];
#pragma unroll
    for (int k = 0; k < 5; ++k) { float2 v = xp[k]; xv[2*k] = v.x; xv[2*k+1] = v.y; }
    int lv[12];
#pragma unroll
    for (int d = 0; d < DD; ++d) lv[d] = qlevel(xv[d], isx);
    lv[10] = 0; lv[11] = 0;
    int xpk[3];
#pragma unroll
    for (int k = 0; k < 3; ++k) xpk[k] = pack4(lv[4*k], lv[4*k+1], lv[4*k+2], lv[4*k+3]);
    float res[20];
#pragma unroll
    for (int j = 0; j < HH; ++j) {
        int ai = 0;
#pragma unroll
        for (int k = 0; k < 3; ++k) ai = dot4(xpk[k], wsi[WS_WIP + j * 3 + k], ai);
        res[j] = (float)ai * prod + wsf[WS_BQ + j];
    }
    float4* op = (float4*)(xw + (size_t)t * BH + b * HH);
#pragma unroll
    for (int k = 0; k < 5; ++k)
        op[k] = make_float4(res[4*k], res[4*k+1], res[4*k+2], res[4*k+3]);
}

// ---------------- kernel 4: serial recurrence, 4 worker blocks ---------------
// Round-9 protocol (same-step validation, line-separated words, single-lane
// remote poll + LDS broadcast, same-XCD placement) widened to 4 blocks:
//  * workers = blockIdx {0,8,16,24} (round-robin mod 8 -> all XCD 0, distinct
//    CUs); 256 threads each own 128 batches.
//  * flag combine: wave 0 lanes 0-2 poll the 3 partner words IN PARALLEL
//    (per-lane addresses -> one memory op per retry), OR via 2 shfl_xor,
//    LDS-broadcast. OR of 4 blocks' flags == flags of global max (monotone).
//  * rare path: every thread polls 3 partners' tagged extrema sequentially
//    (rare). Decisions bit-identical in all blocks.
__global__ __launch_bounds__(256, 4) void k_rnn(const float* __restrict__ h0,
                                                const float* __restrict__ wsf,
                                                const int* __restrict__ wsi,
                                                float* __restrict__ xw,
                                                unsigned* syncp) {
    if (blockIdx.x & 7) return;                 // workers: 0, 8, 16, 24
    __shared__ float2 wred2[4];       // rare path: exact (mx, mn) per wave
    __shared__ int lut8[2][272];      // 2 slots x 257 pre-masked levels (pad 272)
    __shared__ int tagbuf[2];         // (ka<<8) | (kh+128)
    __shared__ int2 rangebuf[2];      // mlvl range for which slot's kh is valid
    __shared__ __align__(8) char flagb[2][4];   // per-wave flags, parity dbuf
    __shared__ unsigned rword[2];     // LDS broadcast of combined remote word
    const int blk = blockIdx.x >> 3;
    const int tid = threadIdx.x;
    const int b = blk * BPB + (tid >> 1);
    const int jb = (tid & 1) * 10;
    const bool isLo = (tid & 1) == 0;
    const int boff = b * HH + jb;
    const int so12 = isLo ? 2 * b : 1024 + 2 * b;
    const float s_wh = wsf[WS_S_WH];
    float sprod = wsf[WS_S_H0] * s_wh;

    if (tid < 2) { tagbuf[tid] = 0x7fffffff; rangebuf[tid] = make_int2(1, 0); rword[tid] = 0; }

    int whp[50];
#pragma unroll
    for (int jj = 0; jj < 10; ++jj)
#pragma unroll
        for (int k = 0; k < 5; ++k)
            whp[jj * 5 + k] = wsi[WS_WHP + (jb + jj) * 5 + k];

    int hd[5];
    {   // h0 -> levels -> pack -> pair exchange
        float ish0 = wsf[WS_INV_SH0];
        const float2* hp = (const float2*)(h0 + boff);
        int lv[10];
#pragma unroll
        for (int k = 0; k < 5; ++k) {
            float2 v = hp[k];
            lv[2*k]   = qlevel(v.x, ish0);
            lv[2*k+1] = qlevel(v.y, ish0);
        }
        mk_hd(pack4(lv[0], lv[1], lv[2], lv[3]),
              pack4(lv[4], lv[5], lv[6], lv[7]),
              (lv[8] & 255) | ((lv[9] & 255) << 8), isLo, hd);
    }
    float bufA[10], bufB[10];
    {
        const float2* p0 = (const float2*)(xw + boff);
#pragma unroll
        for (int k = 0; k < 5; ++k) { float2 v = p0[k]; bufA[2*k] = v.x; bufA[2*k+1] = v.y; }
        const float2* p1 = (const float2*)(xw + BH + boff);
#pragma unroll
        for (int k = 0; k < 5; ++k) { float2 v = p1[k]; bufB[2*k] = v.x; bufB[2*k+1] = v.y; }
    }
    int* lvout = (int*)xw;
    int* lvA = lvout;
    int* lvB = lvout + BH;
    const float2* pfA = (const float2*)(xw + 2 * (size_t)BH + boff);
    const float2* pfB = (const float2*)(xw + 3 * (size_t)BH + boff);
    const int* lutb = &lut8[0][0];

    // cached scale-set state (block-uniform; identical in all 4 blocks)
    float isa = 1.f, sh = 1.f;
    float Whi_f = -1.0f, Wlo_f = 0.0f;     // am > -1 always -> first step rare
    unsigned Koff = 512u - 0x2D000000u;    // slot0: (bits<<2)+Koff = 4r+512

// speculative/redo quantize + pack + stores (reads isa, Koff, sh from scope)
#define QUANT(LVP) do {                                                        \
    _Pragma("unroll")                                                          \
    for (int k = 0; k < 10; ++k) {                                             \
        float tql = fmaf(acc[k], isa, 12582912.0f);       /* 1.5*2^23 */       \
        tql = fmed3(tql, 12582784.0f, 12583040.0f);       /* clamp +-128 */    \
        unsigned a32 = ((unsigned)__float_as_int(tql) << 2) + Koff;            \
        ql[k] = *(const int*)((const char*)lutb + a32);   /* pre-masked */     \
    }                                                                          \
    mk_hd(ql[0] | (ql[1] << 8) | (ql[2] << 16) | (ql[3] << 24),                \
          ql[4] | (ql[5] << 8) | (ql[6] << 16) | (ql[7] << 24),                \
          ql[8] | (ql[9] << 8), isLo, hd);                                     \
    *(int2*)((LVP) + so12) = make_int2(isLo ? hd[0] : hd[2],                   \
                                       isLo ? hd[1] : hd[3]);                  \
    if (!isLo) (LVP)[2048 + b] = hd[4];                                        \
    if (tid == 0 && blk == 0) (LVP)[2560] = __float_as_int(sh);                \
} while (0)

// rare path: exact local reduce + 4-block combine + scale-set rebuild + redo.
// Decisions bit-identical in all blocks (derived from combined values).
#define RARE(LVP, PARX) do {                                                   \
    asm volatile("s_waitcnt vmcnt(0)" ::: "memory");  /* order store rewrite */\
    float mxf = fmaxf(fmaxf(fmaxf(acc[0], acc[1]), fmaxf(acc[2], acc[3])),     \
                fmaxf(fmaxf(acc[4], acc[5]),                                   \
                      fmaxf(fmaxf(acc[6], acc[7]), fmaxf(acc[8], acc[9]))));   \
    float mnf = fminf(fminf(fminf(acc[0], acc[1]), fminf(acc[2], acc[3])),     \
                fminf(fminf(acc[4], acc[5]),                                   \
                      fminf(fminf(acc[6], acc[7]), fminf(acc[8], acc[9]))));   \
    mxf = wave_fmax(mxf);                                                      \
    mnf = wave_fmin(mnf);                                                      \
    if ((tid & 63) == 63) wred2[tid >> 6] = make_float2(mxf, mnf);             \
    BAR();                                                                     \
    float2 w2 = wred2[tid & 3];                                                \
    float rma = row_fmax(w2.x);                                                \
    float rmn = row_fmin(w2.y);                                                \
    if (tid == 0) {            /* publish local extrema (tagged, release) */   \
        unsigned* rb = syncp + SYNR + blk * 32 + (PARX) * 16;                  \
        __hip_atomic_store(rb + 0, (unsigned)__float_as_int(rma),              \
                           __ATOMIC_RELAXED, __HIP_MEMORY_SCOPE_AGENT);        \
        __hip_atomic_store(rb + 1, (unsigned)__float_as_int(rmn),              \
                           __ATOMIC_RELAXED, __HIP_MEMORY_SCOPE_AGENT);        \
        __hip_atomic_store(rb + 2, Tt, __ATOMIC_RELEASE,                       \
                           __HIP_MEMORY_SCOPE_AGENT);                          \
    }                                                                          \
    _Pragma("unroll")                                                          \
    for (int p = 1; p < NW; ++p) {   /* combine with 3 partners (rare) */      \
        const unsigned* rr = syncp + SYNR + (((blk + p) & (NW-1)) * 32) + (PARX) * 16; \
        unsigned tg2;                                                          \
        do { tg2 = __hip_atomic_load(rr + 2, __ATOMIC_ACQUIRE,                 \
                                     __HIP_MEMORY_SCOPE_AGENT); }              \
        while (tg2 != Tt);                                                     \
        float omx = __uint_as_float(__hip_atomic_load(rr + 0, __ATOMIC_RELAXED,\
                                     __HIP_MEMORY_SCOPE_AGENT));               \
        float omn = __uint_as_float(__hip_atomic_load(rr + 1, __ATOMIC_RELAXED,\
                                     __HIP_MEMORY_SCOPE_AGENT));               \
        rma = fmaxf(rma, omx);                                                 \
        rmn = fminf(rmn, omn);                                                 \
    }                                                                          \
    float m_ = fmaxf(fmaxf(rma, -rmn), 1e-10f);                                \
    unsigned uu = __float_as_uint(m_);                                         \
    int ka = (int)(uu >> 23) - 127 + ((uu & 0x7fffffu) ? 1 : 0);               \
    float sa = __uint_as_float((unsigned)(ka + 120) << 23);                    \
    isa = __uint_as_float((unsigned)(134 - ka) << 23);                         \
    float lp = fmed3(rintf(rma * isa), -128.f, 127.f);                         \
    float ln = fmed3(rintf(rmn * isa), -128.f, 127.f);                         \
    int mlvl = (int)fmaxf(fabsf(lp), fabsf(ln));                               \
    int slotn = ka & 1;                                                        \
    int tg = tagbuf[slotn];                                                    \
    int2 rg = rangebuf[slotn];                                                 \
    BAR();   /* all tag/range reads complete before any build writes */        \
    int kh;                                                                    \
    if ((tg >> 8) == ka && mlvl >= rg.x && mlvl <= rg.y) {                     \
        kh = (tg & 255) - 128;           /* LUT slot still valid */            \
    } else {                                                                   \
        kh = khof((float)mlvl, sa);                                            \
        float ish = __uint_as_float((unsigned)(134 - kh) << 23);               \
        if (tid < 256) {                 /* build 257-entry pre-masked LUT */  \
            int qv = tid - 128;                                                \
            float tq = tanhf((float)qv * sa);                                  \
            int lvv = ((int)fmed3(rintf(tq * ish), -128.f, 127.f)) & 255;      \
            lut8[slotn][tid] = lvv;                                            \
            if (tid == 255) lut8[slotn][256] = lvv;  /* entry 256 == 255 */    \
        }                                                                      \
        int lane = tid & 63;                                                   \
        int e0 = khof((float)(2 * lane), sa);                                  \
        int e1 = khof((float)(2 * lane + 1), sa);                              \
        int e2 = khof(128.f, sa);                                              \
        unsigned long long bb0 = __ballot(e0 == kh);                           \
        unsigned long long bb1 = __ballot(e1 == kh);                           \
        int lo = 1000, hi = -1000;                                             \
        if (bb0) { lo = min(lo, 2 * (int)__builtin_ctzll(bb0));                \
                   hi = max(hi, 2 * (63 - (int)__builtin_clzll(bb0))); }       \
        if (bb1) { lo = min(lo, 2 * (int)__builtin_ctzll(bb1) + 1);            \
                   hi = max(hi, 2 * (63 - (int)__builtin_clzll(bb1)) + 1); }   \
        if (e2 == kh && hi == 127) hi = 128;                                   \
        rg = make_int2(lo, hi);                                                \
        if (tid == 0) { tagbuf[slotn] = (ka << 8) | ((kh + 128) & 255);        \
                        rangebuf[slotn] = rg; }                                \
        BAR();   /* LUT + tag visible before any gather */                     \
    }                                                                          \
    sh = __uint_as_float((unsigned)(kh + 120) << 23);                          \
    sprod = sh * s_wh;                                                         \
    Koff = (unsigned)(slotn * 1088 + 512) - 0x2D000000u;                       \
    /* raw-bits validity window for m = max|acc| (conservative edges) */       \
    unsigned wka_lo = ((unsigned)(ka + 126) << 23) + 1u;                       \
    unsigned wka_hi = ((unsigned)(ka + 127) << 23);                            \
    unsigned wlo_m = (rg.x <= 0) ? 0u                                          \
        : (__float_as_uint(((float)rg.x - 0.5f) * sa) + ((rg.x & 1) ? 1u : 0u)); \
    unsigned whi_m = (rg.y >= 128) ? wka_hi                                    \
        : (__float_as_uint(((float)rg.y + 0.5f) * sa) - ((rg.y & 1) ? 1u : 0u)); \
    unsigned Wlo_ = wka_lo > wlo_m ? wka_lo : wlo_m;                           \
    unsigned Whi_ = wka_hi < whi_m ? wka_hi : whi_m;                           \
    Wlo_f = __uint_as_float(Wlo_);                                             \
    Whi_f = __uint_as_float(Whi_);                                             \
    if (rg.x >= 128) Whi_f = -1.0f;   /* empty window: force rare next step */ \
    QUANT(LVP);                                                                \
} while (0)

#define STEP(BUF, TCUR, PAR, PFR, LVP) do {                                    \
    float acc[10];                                                             \
    int ql[10];                                                                \
    _Pragma("unroll")                                                          \
    for (int jj = 0; jj < 10; ++jj) {                                          \
        int ai = 0;                                                            \
        _Pragma("unroll")                                                      \
        for (int k = 0; k < 5; ++k) ai = dot4(hd[k], whp[jj * 5 + k], ai);     \
        acc[jj] = fmaf((float)ai, sprod, BUF[jj]);                             \
    }                                                                          \
    if ((TCUR) + 2 < TT) {   /* prefetch row TCUR+2; old BUF consumed above */ \
        _Pragma("unroll")                                                      \
        for (int k = 0; k < 5; ++k) {                                          \
            float2 v = (PFR)[k]; BUF[2*k] = v.x; BUF[2*k+1] = v.y;             \
        }                                                                      \
    }                                                                          \
    float am = fmaxf(                                                          \
        fmaxf(fmaxf(fabsf(acc[0]), fabsf(acc[1])),                             \
              fmaxf(fabsf(acc[2]), fabsf(acc[3]))),                            \
        fmaxf(fmaxf(fabsf(acc[4]), fabsf(acc[5])),                             \
              fmaxf(fmaxf(fabsf(acc[6]), fabsf(acc[7])),                       \
                    fmaxf(fabsf(acc[8]), fabsf(acc[9])))));                    \
    unsigned long long bh_ = __ballot(am > Whi_f);                             \
    unsigned long long bl_ = __ballot(am >= Wlo_f);                            \
    if ((tid & 63) == 0)                                                       \
        flagb[PAR][tid >> 6] = (char)((bh_ ? 2 : 0) | (bl_ ? 1 : 0));          \
    BAR();   /* the only common-path local barrier */                          \
    const unsigned Tt = ((unsigned)((TCUR) + 1)) << 8;                         \
    if (tid == 0) {          /* publish ASAP so partners' spins are short */   \
        int v0 = *(const int*)&flagb[PAR][0];                                  \
        unsigned lf0 = ((v0 & 0x02020202) ? 2u : 0u) |                         \
                       ((v0 & 0x01010101) ? 1u : 0u);                          \
        __hip_atomic_store(syncp + SYNF + blk * 32 + (PAR) * 16, Tt | lf0,     \
                           __ATOMIC_RELAXED, __HIP_MEMORY_SCOPE_AGENT);        \
    }                                                                          \
    QUANT(LVP);              /* speculative; hides the exchange latency */     \
    int vfl = *(const int*)&flagb[PAR][0];                                     \
    unsigned cf = ((vfl & 0x02020202) ? 2u : 0u) |                             \
                  ((vfl & 0x01010101) ? 1u : 0u);                              \
    {   /* wave 0 lanes 0-2 poll 3 partners in parallel; LDS-broadcast */      \
        if (tid < 64) {                                                        \
            const unsigned* rsl = syncp + SYNF +                               \
                (((blk + 1 + tid) & (NW-1)) * 32) + (PAR) * 16;                \
            unsigned rv = 0;                                                   \
            bool done = tid >= 3;                                              \
            while (!__all(done)) {                                             \
                if (!done) {                                                   \
                    rv = __hip_atomic_load(rsl, __ATOMIC_RELAXED,              \
                                           __HIP_MEMORY_SCOPE_AGENT);          \
                    done = ((rv & 0xFFFFFF00u) == Tt);                         \
                }                                                              \
            }                                                                  \
            unsigned f = (tid < 3) ? (rv & 3u) : 0u;                           \
            f |= (unsigned)__shfl_xor((int)f, 1, 64);                          \
            f |= (unsigned)__shfl_xor((int)f, 2, 64);                          \
            if (tid == 0)                                                      \
                __hip_atomic_store(&rword[PAR], Tt | f, __ATOMIC_RELAXED,      \
                                   __HIP_MEMORY_SCOPE_WORKGROUP);              \
        }                                                                      \
        unsigned rv2;                                                          \
        do { rv2 = __hip_atomic_load(&rword[PAR], __ATOMIC_RELAXED,            \
                                     __HIP_MEMORY_SCOPE_WORKGROUP); }          \
        while ((rv2 & 0xFFFFFF00u) != Tt);                                     \
        cf |= rv2 & 3u;                                                        \
    }                                                                          \
    if (((cf & 2u) != 0u) || ((cf & 1u) == 0u)) {                              \
        RARE(LVP, PAR);                                                        \
    }                                                                          \
} while (0)

    for (int t = 0; t < TT; t += 2) {
        STEP(bufA, t,     0, pfA, lvA);
        STEP(bufB, t + 1, 1, pfB, lvB);
        pfA += BH; pfB += BH;          // advance 2 rows (float2 units)
        lvA += 2 * BH; lvB += 2 * BH;
    }
#undef STEP
#undef RARE
#undef QUANT
}

// ---------------- kernel 5: unpack levels*sh[t] -> [B][T][H] -----------------
__global__ __launch_bounds__(256) void k_tr(const int* __restrict__ lv, float* __restrict__ out) {
    __shared__ int tile[16][5][17];   // [t][plane][b], +1 pad
    __shared__ float shs[16];
    int t0 = blockIdx.x * 16, b0 = blockIdx.y * 16;
    for (int i = threadIdx.x; i < 16 * 5 * 16; i += 256) {
        int t = i / 80, r = i % 80, d = r / 16, bb = r % 16;
        int off = (d < 4) ? ((d >> 1) * 1024 + 2 * (b0 + bb) + (d & 1)) : (2048 + b0 + bb);
        tile[t][d][bb] = lv[(size_t)(t0 + t) * BH + off];
    }
    if (threadIdx.x < 16) shs[threadIdx.x] = __int_as_float(lv[(size_t)(t0 + threadIdx.x) * BH + 2560]);
    __syncthreads();
    for (int i = threadIdx.x; i < 16 * 16 * HH; i += 256) {
        int bb = i / (16 * HH), r = i % (16 * HH), t = r / HH, j = r % HH;
        int w = tile[t][j >> 2][bb];
        int q = (int)(signed char)((w >> (8 * (j & 3))) & 255);
        out[(size_t)(b0 + bb) * (TT * HH) + (size_t)(t0 + t) * HH + j] = (float)q * shs[t];
    }
}

extern "C" void kernel_launch(void* const* d_in, const int* in_sizes, int n_in,
                              void* d_out, int out_size, void* d_ws, size_t ws_size,
                              hipStream_t stream) {
    const float* x    = (const float*)d_in[0];
    const float* h0   = (const float*)d_in[1];
    const float* Wi   = (const float*)d_in[2];
    const float* Wh   = (const float*)d_in[3];
    const float* bias = (const float*)d_in[4];
    float* out = (float*)d_out;

    char* w = (char*)d_ws;
    float* wsf = (float*)w;
    int* wsi = (int*)w;
    unsigned* amax = (unsigned*)w;
    float* xw = (float*)(w + WS_XW_OFF);

    // clear header INCLUDING cross-block sync tags (stale tags would alias)
    (void)hipMemsetAsync(d_ws, 0, 4096, stream);
    int n = in_sizes[0];
    k_amax<<<2048, 256, 0, stream>>>(x, n / 4, amax);
    k_prep<<<1, 256, 0, stream>>>(Wi, Wh, bias, h0, wsf, wsi);
    k_xw<<<(BB * TT) / 256, 256, 0, stream>>>(x, wsf, wsi, xw);
    // 25 blocks: workers are blockIdx 0,8,16,24 (same XCD via round-robin
    // mod 8, distinct CUs); all other blocks exit immediately.
    k_rnn<<<25, 256, 0, stream>>>(h0, wsf, wsi, xw, (unsigned*)w);
    k_tr<<<dim3(TT / 16, BB / 16), 256, 0, stream>>>((const int*)xw, out);
}

// Round 11
// 2379.159 us; speedup vs baseline: 1.2473x; 1.2473x over previous
//
#include <hip/hip_runtime.h>
#include <math.h>

// Problem constants: B=512, T=2048, D=10, H=20
#define BB 512
#define TT 2048
#define DD 10
#define HH 20
#define BH (BB*HH)          // 10240 elements per timestep
#define BPB (BB / 2)        // batches per k_rnn block (2 worker blocks)

// ws layout (word indices from base)
#define WS_AMAX     0
#define WS_PROD_XWI 4
#define WS_INV_SX   5
#define WS_S_H0     6
#define WS_INV_SH0  7
#define WS_S_WH     8
#define WS_BQ       16
#define WS_WIP      40
#define WS_WHP      104
// cross-block sync (cleared by the 4096B memset each launch).
// One cache line per word: block stride 128B, slot stride 64B (no false sharing).
//  flag words:   SYNF + blk*32 + (t&1)*16 -> ((t+1)<<8) | flags
//  rare extrema: SYNR + blk*32 + (t&1)*16 + {0:mx,1:mn,2:tag}
#define SYNF 512
#define SYNR 576
#define WS_XW_OFF   4096    // byte offset of xW buffer: [T][B][H] floats (84 MB)
// per-row reuse: after step t consumes xw row t, k_rnn writes packed int8 levels
// into dwords [0..2559] ({hd0,hd1}@2b, {hd2,hd3}@1024+2b, hd4@2048+b) and
// sh[t] bits into dword 2560 of that row. k_tr reconstructs level*sh exactly.

// LDS-only barrier: never drains vmcnt (prefetch loads / output stores stay in flight)
#define BAR() asm volatile("s_waitcnt lgkmcnt(0)\n\ts_barrier" ::: "memory")

__device__ __forceinline__ int dot4(int a, int b, int c) {
    return __builtin_amdgcn_sdot4(a, b, c, false);
}

// scale = exp2(ceil(log2(max(m,1e-10))))/128 via exponent bits (exact, branchless)
__device__ __forceinline__ void p2s(float m, float* s, float* is) {
    m = fmaxf(m, 1e-10f);
    unsigned u = __float_as_uint(m);
    int k = (int)(u >> 23) - 127 + ((u & 0x7fffffu) ? 1 : 0);  // ceil(log2(m))
    *s  = __uint_as_float((unsigned)(k + 120) << 23);           // 2^(k-7)
    *is = __uint_as_float((unsigned)(134 - k) << 23);           // 2^(7-k)
}

__device__ __forceinline__ float fmed3(float a, float b, float c) {
    return __builtin_amdgcn_fmed3f(a, b, c);
}

__device__ __forceinline__ int qlevel(float v, float inv) {
    return (int)fmed3(rintf(v * inv), -128.f, 127.f);
}

__device__ __forceinline__ int pack4(int a, int b, int c, int d) {
    return (a & 255) | ((b & 255) << 8) | ((c & 255) << 16) | ((d & 255) << 24);
}

// DPP with compile-time ctrl (builtin requires ICE args -> template params).
// old = m, bound_ctrl = 0: lanes with no valid source keep their own value --
// a no-op under max/min, so safe for ANY sign.
template<int CTRL, int RM>
__device__ __forceinline__ float fdpp(float m) {
    return __int_as_float(__builtin_amdgcn_update_dpp(
        __float_as_int(m), __float_as_int(m), CTRL, RM, 0xf, false));
}
// wave64 max: lane63 holds the full-wave max
__device__ __forceinline__ float wave_fmax(float m) {
    m = fmaxf(m, fdpp<0x111, 0xf>(m));  // row_shr1
    m = fmaxf(m, fdpp<0x112, 0xf>(m));  // row_shr2
    m = fmaxf(m, fdpp<0x114, 0xf>(m));  // row_shr4
    m = fmaxf(m, fdpp<0x118, 0xf>(m));  // row_shr8
    m = fmaxf(m, fdpp<0x142, 0xa>(m));  // row_bcast15
    m = fmaxf(m, fdpp<0x143, 0xc>(m));  // row_bcast31
    return m;
}
__device__ __forceinline__ float wave_fmin(float m) {
    m = fminf(m, fdpp<0x111, 0xf>(m));
    m = fminf(m, fdpp<0x112, 0xf>(m));
    m = fminf(m, fdpp<0x114, 0xf>(m));
    m = fminf(m, fdpp<0x118, 0xf>(m));
    m = fminf(m, fdpp<0x142, 0xa>(m));
    m = fminf(m, fdpp<0x143, 0xc>(m));
    return m;
}
// cyclic 16-lane-row reduce: every lane gets its row's max/min
__device__ __forceinline__ float row_fmax(float m) {
    m = fmaxf(m, fdpp<0x121, 0xf>(m));  // row_ror1
    m = fmaxf(m, fdpp<0x122, 0xf>(m));  // row_ror2
    m = fmaxf(m, fdpp<0x124, 0xf>(m));  // row_ror4
    m = fmaxf(m, fdpp<0x128, 0xf>(m));  // row_ror8
    return m;
}
__device__ __forceinline__ float row_fmin(float m) {
    m = fminf(m, fdpp<0x121, 0xf>(m));
    m = fminf(m, fdpp<0x122, 0xf>(m));
    m = fminf(m, fdpp<0x124, 0xf>(m));
    m = fminf(m, fdpp<0x128, 0xf>(m));
    return m;
}

// ceil(log2(max(tanh(mf*sa),1e-10))) -- exponent of the h scale for level mf
__device__ __forceinline__ int khof(float mf, float sa) {
    float mh = fmaxf(tanhf(mf * sa), 1e-10f);
    unsigned u = __float_as_uint(mh);
    return (int)(u >> 23) - 127 + ((u & 0x7fffffu) ? 1 : 0);
}

// pair (lanes 2k,2k+1) h-level merge: 3 quad_perm DPP + byte splices -> hd[5]
// callers guarantee PC fits in 16 bits and PA/PB bytes are pre-masked.
__device__ __forceinline__ void mk_hd(int PA, int PB, int PC, bool isLo, int* hd) {
    int QA = __builtin_amdgcn_update_dpp(0, PA, 0xB1, 0xf, 0xf, true); // quad_perm [1,0,3,2]
    int QB = __builtin_amdgcn_update_dpp(0, PB, 0xB1, 0xf, 0xf, true);
    int QC = __builtin_amdgcn_update_dpp(0, PC, 0xB1, 0xf, 0xf, true);
    int XA = isLo ? PA : QA, XB = isLo ? PB : QB, XC = isLo ? PC : QC;
    int YA = isLo ? QA : PA, YB = isLo ? QB : PB, YC = isLo ? QC : PC;
    hd[0] = XA; hd[1] = XB;
    hd[2] = XC | (YA << 16);
    hd[3] = (int)((unsigned)YA >> 16) | (YB << 16);
    hd[4] = (int)((unsigned)YB >> 16) | (YC << 16);
}

// ---------------- kernel 1: maxabs(x) grid reduction -------------------------
__global__ void k_amax(const float* __restrict__ x, int n4, unsigned* amax) {
    int g = blockIdx.x * blockDim.x + threadIdx.x;
    int stride = gridDim.x * blockDim.x;
    const float4* xv = (const float4*)x;
    float m = 0.f;
    for (int i = g; i < n4; i += stride) {
        float4 v = xv[i];
        m = fmaxf(m, fmaxf(fmaxf(fabsf(v.x), fabsf(v.y)), fmaxf(fabsf(v.z), fabsf(v.w))));
    }
#pragma unroll
    for (int off = 32; off; off >>= 1) m = fmaxf(m, __shfl_xor(m, off, 64));
    if ((threadIdx.x & 63) == 0) atomicMax(amax, __float_as_uint(m));
}

// ---------------- kernel 2: scales + weight quant/pack -----------------------
__device__ float bmaxabs(const float* p, int n, float* red, int tid) {
    float m = 0.f;
    for (int i = tid; i < n; i += 256) m = fmaxf(m, fabsf(p[i]));
    red[tid] = m; __syncthreads();
    for (int s = 128; s; s >>= 1) {
        if (tid < s) red[tid] = fmaxf(red[tid], red[tid + s]);
        __syncthreads();
    }
    m = red[0]; __syncthreads();
    return m;
}

__global__ void k_prep(const float* __restrict__ Wi, const float* __restrict__ Wh,
                       const float* __restrict__ bias, const float* __restrict__ h0,
                       float* wsf, int* wsi) {
    __shared__ float red[256];
    __shared__ float hdr[4];
    int tid = threadIdx.x;
    float mwi = bmaxabs(Wi, HH * DD, red, tid);
    float mwh = bmaxabs(Wh, HH * HH, red, tid);
    float mb  = bmaxabs(bias, HH, red, tid);
    float mh0 = bmaxabs(h0, BH, red, tid);
    if (tid == 0) {
        float mx = __uint_as_float(((unsigned*)wsf)[WS_AMAX]);
        float sx, isx, swi, iswi, swh, iswh, sb, isb, sh0, ish0;
        p2s(mx,  &sx,  &isx);
        p2s(mwi, &swi, &iswi);
        p2s(mwh, &swh, &iswh);
        p2s(mb,  &sb,  &isb);
        p2s(mh0, &sh0, &ish0);
        wsf[WS_PROD_XWI] = sx * swi;
        wsf[WS_INV_SX]   = isx;
        wsf[WS_S_H0]     = sh0;
        wsf[WS_INV_SH0]  = ish0;
        wsf[WS_S_WH]     = swh;
        hdr[0] = iswi; hdr[1] = iswh; hdr[2] = sb; hdr[3] = isb;
    }
    __syncthreads();
    if (tid < HH) {
        float iswi = hdr[0], iswh = hdr[1], sb = hdr[2], isb = hdr[3];
        int lv[20];
#pragma unroll
        for (int d = 0; d < DD; ++d) lv[d] = qlevel(Wi[tid * DD + d], iswi);
        lv[10] = 0; lv[11] = 0;
#pragma unroll
        for (int k = 0; k < 3; ++k)
            wsi[WS_WIP + tid * 3 + k] = pack4(lv[4*k], lv[4*k+1], lv[4*k+2], lv[4*k+3]);
#pragma unroll
        for (int k = 0; k < HH; ++k) lv[k] = qlevel(Wh[tid * HH + k], iswh);
#pragma unroll
        for (int k = 0; k < 5; ++k)
            wsi[WS_WHP + tid * 5 + k] = pack4(lv[4*k], lv[4*k+1], lv[4*k+2], lv[4*k+3]);
        wsf[WS_BQ + tid] = (float)qlevel(bias[tid], isb) * sb;
    }
}

// ---------------- kernel 3: xW[t][b][j] = quant(x)·Wi_q + bq -----------------
__global__ __launch_bounds__(256) void k_xw(const float* __restrict__ x,
                                            const float* __restrict__ wsf,
                                            const int* __restrict__ wsi,
                                            float* __restrict__ xw) {
    int g = blockIdx.x * 256 + threadIdx.x;
    int b = g & (BB - 1);
    int t = g >> 9;
    float isx  = wsf[WS_INV_SX];
    float prod = wsf[WS_PROD_XWI];
    const float2* xp = (const float2*)(x + ((size_t)b * TT + t) * DD);
    float xv[10];
#pragma unroll
    for (int k = 0; k < 5; ++k) { float2 v = xp[k]; xv[2*k] = v.x; xv[2*k+1] = v.y; }
    int lv[12];
#pragma unroll
    for (int d = 0; d < DD; ++d) lv[d] = qlevel(xv[d], isx);
    lv[10] = 0; lv[11] = 0;
    int xpk[3];
#pragma unroll
    for (int k = 0; k < 3; ++k) xpk[k] = pack4(lv[4*k], lv[4*k+1], lv[4*k+2], lv[4*k+3]);
    float res[20];
#pragma unroll
    for (int j = 0; j < HH; ++j) {
        int ai = 0;
#pragma unroll
        for (int k = 0; k < 3; ++k) ai = dot4(xpk[k], wsi[WS_WIP + j * 3 + k], ai);
        res[j] = (float)ai * prod + wsf[WS_BQ + j];
    }
    float4* op = (float4*)(xw + (size_t)t * BH + b * HH);
#pragma unroll
    for (int k = 0; k < 5; ++k)
        op[k] = make_float4(res[4*k], res[4*k+1], res[4*k+2], res[4*k+3]);
}

// ---------------- kernel 4: serial recurrence, 2 worker blocks ---------------
// Round-9 protocol (2 blocks, same-step validation, line-separated words,
// single-lane remote poll + LDS broadcast, same-XCD placement) + one change:
// SOFTWARE-PIPELINED NEXT MATMUL. Step order: prefetch -> fold/ballot -> BAR
// -> publish -> QUANT(acc_cur) -> speculative MATMUL(acc_next) -> poll ->
// (rare: rebuild + requant + REDO matmul). acc entering a step is always
// validated, so published flags are exact -- protocol bit-identical to r9.
// The ~300-400cy of dot4 issue now overlaps the L2 sync RTT that was exposed.
// Prefetch targets the slot NOT needed by a rare redo (other parity).
__global__ __launch_bounds__(512, 4) void k_rnn(const float* __restrict__ h0,
                                                const float* __restrict__ wsf,
                                                const int* __restrict__ wsi,
                                                float* __restrict__ xw,
                                                unsigned* syncp) {
    if (blockIdx.x != 0 && blockIdx.x != 8) return;   // workers: 0 and 8
    __shared__ float2 wred2[8];       // rare path: exact (mx, mn) per wave
    __shared__ int lut8[2][272];      // 2 slots x 257 pre-masked levels (pad 272)
    __shared__ int tagbuf[2];         // (ka<<8) | (kh+128)
    __shared__ int2 rangebuf[2];      // mlvl range for which slot's kh is valid
    __shared__ __align__(16) char flagb[2][8];  // per-wave flags, parity dbuf
    __shared__ unsigned rword[2];     // LDS broadcast of remote word, parity dbuf
    const int blk = blockIdx.x ? 1 : 0;
    const int tid = threadIdx.x;
    const int b = blk * BPB + (tid >> 1);
    const int jb = (tid & 1) * 10;
    const bool isLo = (tid & 1) == 0;
    const int boff = b * HH + jb;
    const int so12 = isLo ? 2 * b : 1024 + 2 * b;
    const float s_wh = wsf[WS_S_WH];
    float sprod = wsf[WS_S_H0] * s_wh;

    if (tid < 2) { tagbuf[tid] = 0x7fffffff; rangebuf[tid] = make_int2(1, 0); rword[tid] = 0; }

    int whp[50];
#pragma unroll
    for (int jj = 0; jj < 10; ++jj)
#pragma unroll
        for (int k = 0; k < 5; ++k)
            whp[jj * 5 + k] = wsi[WS_WHP + (jb + jj) * 5 + k];

    int hd[5];
    {   // h0 -> levels -> pack -> pair exchange
        float ish0 = wsf[WS_INV_SH0];
        const float2* hp = (const float2*)(h0 + boff);
        int lv[10];
#pragma unroll
        for (int k = 0; k < 5; ++k) {
            float2 v = hp[k];
            lv[2*k]   = qlevel(v.x, ish0);
            lv[2*k+1] = qlevel(v.y, ish0);
        }
        mk_hd(pack4(lv[0], lv[1], lv[2], lv[3]),
              pack4(lv[4], lv[5], lv[6], lv[7]),
              (lv[8] & 255) | ((lv[9] & 255) << 8), isLo, hd);
    }

#define MATMUL(DST, SRC) do {                                                  \
    _Pragma("unroll")                                                          \
    for (int jj = 0; jj < 10; ++jj) {                                          \
        int ai = 0;                                                            \
        _Pragma("unroll")                                                      \
        for (int k2 = 0; k2 < 5; ++k2) ai = dot4(hd[k2], whp[jj*5+k2], ai);    \
        (DST)[jj] = fmaf((float)ai, sprod, (SRC)[jj]);                         \
    }                                                                          \
} while (0)

    float bufA[10], bufB[10];
    {
        const float2* p0 = (const float2*)(xw + boff);
#pragma unroll
        for (int k = 0; k < 5; ++k) { float2 v = p0[k]; bufA[2*k] = v.x; bufA[2*k+1] = v.y; }
        const float2* p1 = (const float2*)(xw + BH + boff);
#pragma unroll
        for (int k = 0; k < 5; ++k) { float2 v = p1[k]; bufB[2*k] = v.x; bufB[2*k+1] = v.y; }
    }
    int* lvout = (int*)xw;
    int* lvA = lvout;
    int* lvB = lvout + BH;
    const float2* pfA = (const float2*)(xw + 2 * (size_t)BH + boff);  // rows 2,4,..
    const float2* pfB = (const float2*)(xw + 3 * (size_t)BH + boff);  // rows 3,5,..
    const int* lutb = &lut8[0][0];

    // cached scale-set state (block-uniform; identical in both blocks)
    float isa = 1.f, sh = 1.f;
    float Whi_f = -1.0f, Wlo_f = 0.0f;     // am > -1 always -> first step rare
    unsigned Koff = 512u - 0x2D000000u;    // slot0: (bits<<2)+Koff = 4r+512

    float acc0[10], acc1[10];
    MATMUL(acc0, bufA);                    // acc for step 0 (exact: h0 state)

// quantize + pack + stores from ACCX (reads isa, Koff, sh from scope)
#define QUANT(ACCX, LVP) do {                                                  \
    int ql[10];                                                                \
    _Pragma("unroll")                                                          \
    for (int k = 0; k < 10; ++k) {                                             \
        float tql = fmaf((ACCX)[k], isa, 12582912.0f);    /* 1.5*2^23 */       \
        tql = fmed3(tql, 12582784.0f, 12583040.0f);       /* clamp +-128 */    \
        unsigned a32 = ((unsigned)__float_as_int(tql) << 2) + Koff;            \
        ql[k] = *(const int*)((const char*)lutb + a32);   /* pre-masked */     \
    }                                                                          \
    mk_hd(ql[0] | (ql[1] << 8) | (ql[2] << 16) | (ql[3] << 24),                \
          ql[4] | (ql[5] << 8) | (ql[6] << 16) | (ql[7] << 24),                \
          ql[8] | (ql[9] << 8), isLo, hd);                                     \
    *(int2*)((LVP) + so12) = make_int2(isLo ? hd[0] : hd[2],                   \
                                       isLo ? hd[1] : hd[3]);                  \
    if (!isLo) (LVP)[2048 + b] = hd[4];                                        \
    if (tid == 0 && blk == 0) (LVP)[2560] = __float_as_int(sh);                \
} while (0)

// rare path: exact local reduce of ACCX + cross-block combine + scale-set
// rebuild + requant/re-store. Decisions bit-identical in both blocks.
#define RARE(ACCX, LVP, PARX) do {                                             \
    asm volatile("s_waitcnt vmcnt(0)" ::: "memory");  /* order store rewrite */\
    float mxf = fmaxf(fmaxf(fmaxf((ACCX)[0], (ACCX)[1]), fmaxf((ACCX)[2], (ACCX)[3])), \
                fmaxf(fmaxf((ACCX)[4], (ACCX)[5]),                             \
                      fmaxf(fmaxf((ACCX)[6], (ACCX)[7]), fmaxf((ACCX)[8], (ACCX)[9])))); \
    float mnf = fminf(fminf(fminf((ACCX)[0], (ACCX)[1]), fminf((ACCX)[2], (ACCX)[3])), \
                fminf(fminf((ACCX)[4], (ACCX)[5]),                             \
                      fminf(fminf((ACCX)[6], (ACCX)[7]), fminf((ACCX)[8], (ACCX)[9])))); \
    mxf = wave_fmax(mxf);                                                      \
    mnf = wave_fmin(mnf);                                                      \
    if ((tid & 63) == 63) wred2[tid >> 6] = make_float2(mxf, mnf);             \
    BAR();                                                                     \
    float2 w2 = wred2[tid & 7];                                                \
    float rma = row_fmax(w2.x);                                                \
    float rmn = row_fmin(w2.y);                                                \
    if (tid == 0) {            /* publish local extrema (tagged, release) */   \
        unsigned* rb = syncp + SYNR + blk * 32 + (PARX) * 16;                  \
        __hip_atomic_store(rb + 0, (unsigned)__float_as_int(rma),              \
                           __ATOMIC_RELAXED, __HIP_MEMORY_SCOPE_AGENT);        \
        __hip_atomic_store(rb + 1, (unsigned)__float_as_int(rmn),              \
                           __ATOMIC_RELAXED, __HIP_MEMORY_SCOPE_AGENT);        \
        __hip_atomic_store(rb + 2, Tt, __ATOMIC_RELEASE,                       \
                           __HIP_MEMORY_SCOPE_AGENT);                          \
    }                                                                          \
    {                          /* combine with partner's extrema */            \
        const unsigned* rr = syncp + SYNR + (blk ^ 1) * 32 + (PARX) * 16;      \
        unsigned tg2;                                                          \
        do { tg2 = __hip_atomic_load(rr + 2, __ATOMIC_ACQUIRE,                 \
                                     __HIP_MEMORY_SCOPE_AGENT); }              \
        while (tg2 != Tt);                                                     \
        float omx = __uint_as_float(__hip_atomic_load(rr + 0, __ATOMIC_RELAXED,\
                                     __HIP_MEMORY_SCOPE_AGENT));               \
        float omn = __uint_as_float(__hip_atomic_load(rr + 1, __ATOMIC_RELAXED,\
                                     __HIP_MEMORY_SCOPE_AGENT));               \
        rma = fmaxf(rma, omx);                                                 \
        rmn = fminf(rmn, omn);                                                 \
    }                                                                          \
    float m_ = fmaxf(fmaxf(rma, -rmn), 1e-10f);                                \
    unsigned uu = __float_as_uint(m_);                                         \
    int ka = (int)(uu >> 23) - 127 + ((uu & 0x7fffffu) ? 1 : 0);               \
    float sa = __uint_as_float((unsigned)(ka + 120) << 23);                    \
    isa = __uint_as_float((unsigned)(134 - ka) << 23);                         \
    float lp = fmed3(rintf(rma * isa), -128.f, 127.f);                         \
    float ln = fmed3(rintf(rmn * isa), -128.f, 127.f);                         \
    int mlvl = (int)fmaxf(fabsf(lp), fabsf(ln));                               \
    int slotn = ka & 1;                                                        \
    int tg = tagbuf[slotn];                                                    \
    int2 rg = rangebuf[slotn];                                                 \
    BAR();   /* all tag/range reads complete before any build writes */        \
    int kh;                                                                    \
    if ((tg >> 8) == ka && mlvl >= rg.x && mlvl <= rg.y) {                     \
        kh = (tg & 255) - 128;           /* LUT slot still valid */            \
    } else {                                                                   \
        kh = khof((float)mlvl, sa);                                            \
        float ish = __uint_as_float((unsigned)(134 - kh) << 23);               \
        if (tid < 257) {                 /* build 257-entry pre-masked LUT */  \
            int qv = (tid < 256 ? tid : 255) - 128;                            \
            float tq = tanhf((float)qv * sa);                                  \
            lut8[slotn][tid] = ((int)fmed3(rintf(tq * ish), -128.f, 127.f)) & 255; \
        }                                                                      \
        int lane = tid & 63;                                                   \
        int e0 = khof((float)(2 * lane), sa);                                  \
        int e1 = khof((float)(2 * lane + 1), sa);                              \
        int e2 = khof(128.f, sa);                                              \
        unsigned long long bb0 = __ballot(e0 == kh);                           \
        unsigned long long bb1 = __ballot(e1 == kh);                           \
        int lo = 1000, hi = -1000;                                             \
        if (bb0) { lo = min(lo, 2 * (int)__builtin_ctzll(bb0));                \
                   hi = max(hi, 2 * (63 - (int)__builtin_clzll(bb0))); }       \
        if (bb1) { lo = min(lo, 2 * (int)__builtin_ctzll(bb1) + 1);            \
                   hi = max(hi, 2 * (63 - (int)__builtin_clzll(bb1)) + 1); }   \
        if (e2 == kh && hi == 127) hi = 128;                                   \
        rg = make_int2(lo, hi);                                                \
        if (tid == 0) { tagbuf[slotn] = (ka << 8) | ((kh + 128) & 255);        \
                        rangebuf[slotn] = rg; }                                \
        BAR();   /* LUT + tag visible before any gather */                     \
    }                                                                          \
    sh = __uint_as_float((unsigned)(kh + 120) << 23);                          \
    sprod = sh * s_wh;                                                         \
    Koff = (unsigned)(slotn * 1088 + 512) - 0x2D000000u;                       \
    /* raw-bits validity window for m = max|acc| (conservative edges) */       \
    unsigned wka_lo = ((unsigned)(ka + 126) << 23) + 1u;                       \
    unsigned wka_hi = ((unsigned)(ka + 127) << 23);                            \
    unsigned wlo_m = (rg.x <= 0) ? 0u                                          \
        : (__float_as_uint(((float)rg.x - 0.5f) * sa) + ((rg.x & 1) ? 1u : 0u)); \
    unsigned whi_m = (rg.y >= 128) ? wka_hi                                    \
        : (__float_as_uint(((float)rg.y + 0.5f) * sa) - ((rg.y & 1) ? 1u : 0u)); \
    unsigned Wlo_ = wka_lo > wlo_m ? wka_lo : wlo_m;                           \
    unsigned Whi_ = wka_hi < whi_m ? wka_hi : whi_m;                           \
    Wlo_f = __uint_as_float(Wlo_);                                             \
    Whi_f = __uint_as_float(Whi_);                                             \
    if (rg.x >= 128) Whi_f = -1.0f;   /* empty window: force rare next step */ \
    QUANT(ACCX, LVP);                                                          \
} while (0)

// ACCC: validated acc for step TCUR. ACCN: speculative acc for step TCUR+1.
// PREB/PFR: prefetch row TCUR+2 into the slot a rare redo does NOT need.
// NXTB: register buffer holding row TCUR+1 (input of the speculative matmul).
#define STEP(ACCC, ACCN, TCUR, PAR, PFR, PREB, NXTB, LVP) do {                 \
    if ((TCUR) + 2 < TT) {   /* early prefetch; loads fly across barriers */   \
        _Pragma("unroll")                                                      \
        for (int k = 0; k < 5; ++k) {                                          \
            float2 v = (PFR)[k]; (PREB)[2*k] = v.x; (PREB)[2*k+1] = v.y;       \
        }                                                                      \
    }                                                                          \
    float am = fmaxf(                                                          \
        fmaxf(fmaxf(fabsf((ACCC)[0]), fabsf((ACCC)[1])),                       \
              fmaxf(fabsf((ACCC)[2]), fabsf((ACCC)[3]))),                      \
        fmaxf(fmaxf(fabsf((ACCC)[4]), fabsf((ACCC)[5])),                       \
              fmaxf(fmaxf(fabsf((ACCC)[6]), fabsf((ACCC)[7])),                 \
                    fmaxf(fabsf((ACCC)[8]), fabsf((ACCC)[9])))));              \
    unsigned long long bh_ = __ballot(am > Whi_f);                             \
    unsigned long long bl_ = __ballot(am >= Wlo_f);                            \
    if ((tid & 63) == 0)                                                       \
        flagb[PAR][tid >> 6] = (char)((bh_ ? 2 : 0) | (bl_ ? 1 : 0));          \
    BAR();   /* the only common-path local barrier */                          \
    const unsigned Tt = ((unsigned)((TCUR) + 1)) << 8;                         \
    if (tid == 0) {          /* publish ASAP so partner's spin is short */     \
        int2 f0 = *(const int2*)&flagb[PAR][0];                                \
        int v0 = f0.x | f0.y;                                                  \
        unsigned lf0 = ((v0 & 0x02020202) ? 2u : 0u) |                         \
                       ((v0 & 0x01010101) ? 1u : 0u);                          \
        __hip_atomic_store(syncp + SYNF + blk * 32 + (PAR) * 16, Tt | lf0,     \
                           __ATOMIC_RELAXED, __HIP_MEMORY_SCOPE_AGENT);        \
    }                                                                          \
    QUANT(ACCC, LVP);        /* speculative quantize + store + hd update */    \
    if ((TCUR) + 1 < TT) MATMUL(ACCN, NXTB);   /* speculative next matmul */   \
    int2 fv = *(const int2*)&flagb[PAR][0];                                    \
    int vfl = fv.x | fv.y;                                                     \
    unsigned cf = ((vfl & 0x02020202) ? 2u : 0u) |                             \
                  ((vfl & 0x01010101) ? 1u : 0u);                              \
    {                        /* tid0 polls remote; LDS-broadcast to others */  \
        if (tid == 0) {                                                        \
            const unsigned* rsl = syncp + SYNF + (blk ^ 1) * 32 + (PAR) * 16;  \
            unsigned rv;                                                       \
            do { rv = __hip_atomic_load(rsl, __ATOMIC_RELAXED,                 \
                                        __HIP_MEMORY_SCOPE_AGENT); }           \
            while ((rv & 0xFFFFFF00u) != Tt);                                  \
            __hip_atomic_store(&rword[PAR], rv, __ATOMIC_RELAXED,              \
                               __HIP_MEMORY_SCOPE_WORKGROUP);                  \
        }                                                                      \
        unsigned rv2;                                                          \
        do { rv2 = __hip_atomic_load(&rword[PAR], __ATOMIC_RELAXED,            \
                                     __HIP_MEMORY_SCOPE_WORKGROUP); }          \
        while ((rv2 & 0xFFFFFF00u) != Tt);                                     \
        cf |= rv2 & 3u;                                                        \
    }                                                                          \
    if (((cf & 2u) != 0u) || ((cf & 1u) == 0u)) {                              \
        RARE(ACCC, LVP, PAR);              /* rebuild + requant + re-store */  \
        if ((TCUR) + 1 < TT) MATMUL(ACCN, NXTB);   /* redo with fixed hd */    \
    }                                                                          \
} while (0)

    for (int t = 0; t < TT; t += 2) {
        // even step t: acc0 current; prefetch row t+2 -> bufA (freed; a rare
        // redo needs bufB=row t+1, untouched); next matmul reads bufB.
        STEP(acc0, acc1, t,     0, pfA, bufA, bufB, lvA);
        // odd step t+1: acc1 current; prefetch row t+3 -> bufB; next matmul
        // reads bufA (= row t+2, prefetched one step ago).
        STEP(acc1, acc0, t + 1, 1, pfB, bufB, bufA, lvB);
        pfA += BH; pfB += BH;          // advance 2 rows (float2 units)
        lvA += 2 * BH; lvB += 2 * BH;
    }
#undef STEP
#undef RARE
#undef QUANT
#undef MATMUL
}

// ---------------- kernel 5: unpack levels*sh[t] -> [B][T][H] -----------------
__global__ __launch_bounds__(256) void k_tr(const int* __restrict__ lv, float* __restrict__ out) {
    __shared__ int tile[16][5][17];   // [t][plane][b], +1 pad
    __shared__ float shs[16];
    int t0 = blockIdx.x * 16, b0 = blockIdx.y * 16;
    for (int i = threadIdx.x; i < 16 * 5 * 16; i += 256) {
        int t = i / 80, r = i % 80, d = r / 16, bb = r % 16;
        int off = (d < 4) ? ((d >> 1) * 1024 + 2 * (b0 + bb) + (d & 1)) : (2048 + b0 + bb);
        tile[t][d][bb] = lv[(size_t)(t0 + t) * BH + off];
    }
    if (threadIdx.x < 16) shs[threadIdx.x] = __int_as_float(lv[(size_t)(t0 + threadIdx.x) * BH + 2560]);
    __syncthreads();
    for (int i = threadIdx.x; i < 16 * 16 * HH; i += 256) {
        int bb = i / (16 * HH), r = i % (16 * HH), t = r / HH, j = r % HH;
        int w = tile[t][j >> 2][bb];
        int q = (int)(signed char)((w >> (8 * (j & 3))) & 255);
        out[(size_t)(b0 + bb) * (TT * HH) + (size_t)(t0 + t) * HH + j] = (float)q * shs[t];
    }
}

extern "C" void kernel_launch(void* const* d_in, const int* in_sizes, int n_in,
                              void* d_out, int out_size, void* d_ws, size_t ws_size,
                              hipStream_t stream) {
    const float* x    = (const float*)d_in[0];
    const float* h0   = (const float*)d_in[1];
    const float* Wi   = (const float*)d_in[2];
    const float* Wh   = (const float*)d_in[3];
    const float* bias = (const float*)d_in[4];
    float* out = (float*)d_out;

    char* w = (char*)d_ws;
    float* wsf = (float*)w;
    int* wsi = (int*)w;
    unsigned* amax = (unsigned*)w;
    float* xw = (float*)(w + WS_XW_OFF);

    // clear header INCLUDING cross-block sync tags (stale tags would alias)
    (void)hipMemsetAsync(d_ws, 0, 4096, stream);
    int n = in_sizes[0];
    k_amax<<<2048, 256, 0, stream>>>(x, n / 4, amax);
    k_prep<<<1, 256, 0, stream>>>(Wi, Wh, bias, h0, wsf, wsi);
    k_xw<<<(BB * TT) / 256, 256, 0, stream>>>(x, wsf, wsi, xw);
    // 9 blocks: workers are blockIdx 0 and 8 (same XCD via round-robin mod 8);
    // blocks 1-7 exit immediately.
    k_rnn<<<9, 512, 0, stream>>>(h0, wsf, wsi, xw, (unsigned*)w);
    k_tr<<<dim3(TT / 16, BB / 16), 256, 0, stream>>>((const int*)xw, out);
}